// Round 1
// baseline (2678.016 us; speedup 1.0000x reference)
//
#include <hip/hip_runtime.h>
#include <hip/hip_bf16.h>

#define HH 256
#define WW 256
#define BB 4
#define CC 32

constexpr int TILE_W = 64;
constexpr int TILE_H = 4;

// ---------------------------------------------------------------------------
// Fold BN into conv weights/bias; transpose final conv weights to [ci][co][9]
// ---------------------------------------------------------------------------
__global__ void fold_weights(
    const float* __restrict__ wconv,   // [4][2][32][32][3][3]
    const float* __restrict__ bconv,   // [4][2][32]
    const float* __restrict__ g,       // [4][2][32]
    const float* __restrict__ beta,    // [4][2][32]
    const float* __restrict__ mu,      // [4][2][32]
    const float* __restrict__ var,     // [4][2][32]
    const float* __restrict__ w_final, // [32][128][3][3]
    float* __restrict__ wfold,         // [8][ci=32][co=32][9]
    float* __restrict__ bfold,         // [8][32]
    float* __restrict__ wT)            // [ci=128][co=32][9]
{
    int idx = blockIdx.x * 256 + threadIdx.x;
    if (idx < 8 * 9216) {
        int v = idx / 9216, r = idx % 9216;
        int ci = r / 288, r2 = r % 288;
        int co = r2 / 9, t = r2 % 9;
        float s = g[v * 32 + co] / sqrtf(var[v * 32 + co] + 1e-5f);
        wfold[idx] = wconv[(((v * 32 + co) * 32 + ci) * 9) + t] * s;
    } else if (idx < 8 * 9216 + 256) {
        int i = idx - 8 * 9216;
        float s = g[i] / sqrtf(var[i] + 1e-5f);
        bfold[i] = (bconv[i] - mu[i]) * s + beta[i];
    } else if (idx < 8 * 9216 + 256 + 36864) {
        int i = idx - (8 * 9216 + 256);
        int ci = i / 288, r2 = i % 288;
        int co = r2 / 9, t = r2 % 9;
        wT[i] = w_final[((size_t)co * 128 + ci) * 9 + t];
    }
}

// ---------------------------------------------------------------------------
// conv3x3 (BN folded) + optional residual add + ReLU
// in: [B,32,H,W]  wf: [ci=32][co=32][9]  bf: [32]
// ---------------------------------------------------------------------------
template <bool RESID>
__global__ __launch_bounds__(256) void conv3x3_fused(
    const float* __restrict__ in,
    const float* __restrict__ wf,
    const float* __restrict__ bf,
    const float* __restrict__ resid,
    float* __restrict__ out)
{
    __shared__ float tile[32][TILE_H + 2][TILE_W + 2];
    const int bx = blockIdx.x;   // W / TILE_W
    const int by = blockIdx.y;   // H / TILE_H
    const int b  = blockIdx.z;
    const int tid = threadIdx.x;
    const int tx = tid & 63, ty = tid >> 6;

    // stage input tile (with halo, zero-padded)
    const float* inb = in + (size_t)b * 32 * HH * WW;
    constexpr int NE = 32 * (TILE_H + 2) * (TILE_W + 2);
    for (int idx = tid; idx < NE; idx += 256) {
        int ci  = idx / ((TILE_H + 2) * (TILE_W + 2));
        int rem = idx % ((TILE_H + 2) * (TILE_W + 2));
        int r = rem / (TILE_W + 2), c = rem % (TILE_W + 2);
        int gy = by * TILE_H + r - 1;
        int gx = bx * TILE_W + c - 1;
        float v = 0.f;
        if ((unsigned)gy < HH && (unsigned)gx < WW)
            v = inb[(size_t)ci * (HH * WW) + (size_t)gy * WW + gx];
        tile[ci][r][c] = v;
    }
    __syncthreads();

    float acc[32];
    #pragma unroll
    for (int co = 0; co < 32; ++co) acc[co] = bf[co];

    for (int ci = 0; ci < 32; ++ci) {
        float v[9];
        #pragma unroll
        for (int dy = 0; dy < 3; ++dy)
            #pragma unroll
            for (int dx = 0; dx < 3; ++dx)
                v[dy * 3 + dx] = tile[ci][ty + dy][tx + dx];
        const float* w = wf + ci * 288;
        #pragma unroll
        for (int co = 0; co < 32; ++co) {
            #pragma unroll
            for (int t = 0; t < 9; ++t)
                acc[co] += v[t] * w[co * 9 + t];
        }
    }

    const int y = by * TILE_H + ty, x = bx * TILE_W + tx;
    const size_t o = (size_t)b * 32 * HH * WW + (size_t)y * WW + x;
    #pragma unroll
    for (int co = 0; co < 32; ++co) {
        float r = acc[co];
        if (RESID) r += resid[o + (size_t)co * (HH * WW)];
        out[o + (size_t)co * (HH * WW)] = fmaxf(r, 0.f);
    }
}

// ---------------------------------------------------------------------------
// m5 = relu(m - tau); core = 1x1 conv (C -> C*9); pred for rates 1..4
// writes pred_cat [B][128][H][W]
// ---------------------------------------------------------------------------
__global__ __launch_bounds__(256) void core_pred(
    const float* __restrict__ m,      // [B,32,H,W]
    const float* __restrict__ inp,    // [B,32,H,W]
    const float* __restrict__ tau,    // [32]
    const float* __restrict__ w_outc, // [288][32]
    const float* __restrict__ b_outc, // [288]
    float* __restrict__ pred)         // [B,128,H,W]
{
    const int bx = blockIdx.x;
    const int by = blockIdx.y;
    const int b  = blockIdx.z;
    const int tid = threadIdx.x;
    const int tx = tid & 63, ty = tid >> 6;
    const int y = by * TILE_H + ty, x = bx * TILE_W + tx;

    const size_t base = (size_t)b * 32 * HH * WW + (size_t)y * WW + x;
    float m5[32];
    #pragma unroll
    for (int c = 0; c < 32; ++c)
        m5[c] = fmaxf(m[base + (size_t)c * (HH * WW)] - tau[c], 0.f);

    for (int n = 0; n < 32; ++n) {
        float ck[9];
        #pragma unroll
        for (int k = 0; k < 9; ++k) {
            float a = b_outc[n * 9 + k];
            const float* w = w_outc + (size_t)(n * 9 + k) * 32;
            #pragma unroll
            for (int c = 0; c < 32; ++c) a += m5[c] * w[c];
            ck[k] = a;
        }
        const float* inpn = inp + (size_t)b * 32 * HH * WW + (size_t)n * (HH * WW);
        #pragma unroll
        for (int r = 1; r <= 4; ++r) {
            float s = 0.f;
            #pragma unroll
            for (int i = 0; i < 3; ++i) {
                int yy = y + (i - 1) * r;
                #pragma unroll
                for (int j = 0; j < 3; ++j) {
                    int xx = x + (j - 1) * r;
                    float fv = 0.f;
                    if ((unsigned)yy < HH && (unsigned)xx < WW)
                        fv = inpn[(size_t)yy * WW + xx];
                    s += ck[i * 3 + j] * fv;
                }
            }
            pred[(((size_t)b * 128 + (r - 1) * 32 + n) * HH + y) * WW + x] = s;
        }
    }
}

// ---------------------------------------------------------------------------
// final conv3x3: 128 -> 32, pad 1, + bias (no activation)
// wT: [ci=128][co=32][9]
// ---------------------------------------------------------------------------
__global__ __launch_bounds__(256) void final_conv(
    const float* __restrict__ pred,  // [B,128,H,W]
    const float* __restrict__ wT,
    const float* __restrict__ bfin,  // [32]
    float* __restrict__ out)         // [B,32,H,W]
{
    __shared__ float tile[32][TILE_H + 2][TILE_W + 2];
    const int bx = blockIdx.x;
    const int by = blockIdx.y;
    const int b  = blockIdx.z;
    const int tid = threadIdx.x;
    const int tx = tid & 63, ty = tid >> 6;

    float acc[32];
    #pragma unroll
    for (int co = 0; co < 32; ++co) acc[co] = bfin[co];

    for (int chunk = 0; chunk < 4; ++chunk) {
        __syncthreads();   // protect previous chunk's reads
        const float* inb = pred + ((size_t)b * 128 + chunk * 32) * (HH * WW);
        constexpr int NE = 32 * (TILE_H + 2) * (TILE_W + 2);
        for (int idx = tid; idx < NE; idx += 256) {
            int ci  = idx / ((TILE_H + 2) * (TILE_W + 2));
            int rem = idx % ((TILE_H + 2) * (TILE_W + 2));
            int r = rem / (TILE_W + 2), c = rem % (TILE_W + 2);
            int gy = by * TILE_H + r - 1;
            int gx = bx * TILE_W + c - 1;
            float v = 0.f;
            if ((unsigned)gy < HH && (unsigned)gx < WW)
                v = inb[(size_t)ci * (HH * WW) + (size_t)gy * WW + gx];
            tile[ci][r][c] = v;
        }
        __syncthreads();

        for (int cil = 0; cil < 32; ++cil) {
            float v[9];
            #pragma unroll
            for (int dy = 0; dy < 3; ++dy)
                #pragma unroll
                for (int dx = 0; dx < 3; ++dx)
                    v[dy * 3 + dx] = tile[cil][ty + dy][tx + dx];
            const float* w = wT + (size_t)(chunk * 32 + cil) * 288;
            #pragma unroll
            for (int co = 0; co < 32; ++co) {
                #pragma unroll
                for (int t = 0; t < 9; ++t)
                    acc[co] += v[t] * w[co * 9 + t];
            }
        }
    }

    const int y = by * TILE_H + ty, x = bx * TILE_W + tx;
    const size_t o = (size_t)b * 32 * HH * WW + (size_t)y * WW + x;
    #pragma unroll
    for (int co = 0; co < 32; ++co)
        out[o + (size_t)co * (HH * WW)] = acc[co];
}

// ---------------------------------------------------------------------------
extern "C" void kernel_launch(void* const* d_in, const int* in_sizes, int n_in,
                              void* d_out, int out_size, void* d_ws, size_t ws_size,
                              hipStream_t stream)
{
    const float* input    = (const float*)d_in[0];
    const float* wconv    = (const float*)d_in[1];
    const float* bconv    = (const float*)d_in[2];
    const float* bn_gamma = (const float*)d_in[3];
    const float* bn_beta  = (const float*)d_in[4];
    const float* bn_mean  = (const float*)d_in[5];
    const float* bn_var   = (const float*)d_in[6];
    const float* tau      = (const float*)d_in[7];
    const float* w_outc   = (const float*)d_in[8];
    const float* b_outc   = (const float*)d_in[9];
    const float* w_final  = (const float*)d_in[10];
    const float* b_final  = (const float*)d_in[11];
    float* out = (float*)d_out;

    float* ws    = (float*)d_ws;
    float* wfold = ws;                       // 73728
    float* bfold = ws + 73728;               // 256
    float* wT    = ws + 73984;               // 36864  (end 110848)
    const size_t ACT = (size_t)BB * CC * HH * WW;  // 8388608
    float* A    = ws + 110848;
    float* Bbuf = A + ACT;
    float* Cbuf = Bbuf + ACT;
    float* pred = Cbuf + ACT;                // 4*ACT floats

    fold_weights<<<(110848 + 255) / 256, 256, 0, stream>>>(
        wconv, bconv, bn_gamma, bn_beta, bn_mean, bn_var, w_final,
        wfold, bfold, wT);

    dim3 grid(WW / TILE_W, HH / TILE_H, BB);
    dim3 blk(256);

    // res block 1
    conv3x3_fused<false><<<grid, blk, 0, stream>>>(input, wfold + 0 * 9216, bfold + 0,  nullptr, A);
    conv3x3_fused<true ><<<grid, blk, 0, stream>>>(A,     wfold + 1 * 9216, bfold + 32, input,   Bbuf);
    // res block 2
    conv3x3_fused<false><<<grid, blk, 0, stream>>>(Bbuf,  wfold + 2 * 9216, bfold + 64, nullptr, A);
    conv3x3_fused<true ><<<grid, blk, 0, stream>>>(A,     wfold + 3 * 9216, bfold + 96, Bbuf,    Cbuf);
    // res block 3
    conv3x3_fused<false><<<grid, blk, 0, stream>>>(Cbuf,  wfold + 4 * 9216, bfold + 128, nullptr, A);
    conv3x3_fused<true ><<<grid, blk, 0, stream>>>(A,     wfold + 5 * 9216, bfold + 160, Cbuf,    Bbuf);
    // res block 4
    conv3x3_fused<false><<<grid, blk, 0, stream>>>(Bbuf,  wfold + 6 * 9216, bfold + 192, nullptr, A);
    conv3x3_fused<true ><<<grid, blk, 0, stream>>>(A,     wfold + 7 * 9216, bfold + 224, Bbuf,    Cbuf);

    core_pred<<<grid, blk, 0, stream>>>(Cbuf, input, tau, w_outc, b_outc, pred);

    final_conv<<<grid, blk, 0, stream>>>(pred, wT, b_final, out);
}

// Round 2
// 254.569 us; speedup vs baseline: 10.5198x; 10.5198x over previous
//
#include <hip/hip_runtime.h>

typedef __bf16 bf16;
typedef __attribute__((ext_vector_type(8))) __bf16 bf16x8;
typedef __attribute__((ext_vector_type(4))) float f32x4;

#define HH 256
#define WW 256
#define NPIX 65536

__device__ inline bf16x8 bzero8() {
    bf16x8 v;
    #pragma unroll
    for (int i = 0; i < 8; ++i) v[i] = (bf16)0.0f;
    return v;
}

// ---------------------------------------------------------------------------
// input NCHW fp32 -> NHWC bf16
// ---------------------------------------------------------------------------
__global__ __launch_bounds__(256) void prep_in(const float* __restrict__ in,
                                               bf16* __restrict__ out) {
    int p = blockIdx.x * 256 + threadIdx.x;   // 0..262143 = b*65536 + y*256 + x
    int b = p >> 16, rem = p & 65535;
    #pragma unroll
    for (int cg = 0; cg < 4; ++cg) {
        bf16x8 v;
        #pragma unroll
        for (int j = 0; j < 8; ++j)
            v[j] = (bf16)in[(size_t)(b * 32 + cg * 8 + j) * NPIX + rem];
        *reinterpret_cast<bf16x8*>(out + (size_t)p * 32 + cg * 8) = v;
    }
}

// ---------------------------------------------------------------------------
// Fold BN into conv weights (bf16, layout [layer][tap][co][ci]); core weights
// [tap][nn][ci]; final weights [chunk][tap][co][ci].
// ---------------------------------------------------------------------------
__global__ void fold_w(const float* __restrict__ wconv, const float* __restrict__ bconv,
                       const float* __restrict__ g, const float* __restrict__ beta,
                       const float* __restrict__ mu, const float* __restrict__ var,
                       const float* __restrict__ w_outc, const float* __restrict__ w_final,
                       bf16* __restrict__ Wres, float* __restrict__ Bres,
                       bf16* __restrict__ Wcore, bf16* __restrict__ Wfin) {
    int idx = blockIdx.x * 256 + threadIdx.x;
    if (idx < 73728) {
        int l = idx / 9216, r = idx % 9216;
        int tap = r >> 10, co = (r >> 5) & 31, ci = r & 31;
        float s = g[l * 32 + co] * rsqrtf(var[l * 32 + co] + 1e-5f);
        Wres[idx] = (bf16)(wconv[l * 9216 + (co * 32 + ci) * 9 + tap] * s);
    } else if (idx < 73984) {
        int i = idx - 73728;
        float s = g[i] * rsqrtf(var[i] + 1e-5f);
        Bres[i] = (bconv[i] - mu[i]) * s + beta[i];
    } else if (idx < 83200) {
        int r = idx - 73984;
        int tap = r >> 10, nn = (r >> 5) & 31, ci = r & 31;
        Wcore[r] = (bf16)w_outc[(nn * 9 + tap) * 32 + ci];
    } else if (idx < 120064) {
        int r = idx - 83200;
        int chunk = r / 9216, r2 = r % 9216;
        int tap = r2 >> 10, co = (r2 >> 5) & 31, ci = r2 & 31;
        Wfin[r] = (bf16)w_final[(size_t)(co * 128 + chunk * 32 + ci) * 9 + tap];
    }
}

// ---------------------------------------------------------------------------
// conv3x3 (32->32) MFMA implicit GEMM, NHWC bf16, BN folded, +resid, ReLU
// wB: [9][co 32][ci 32] bf16.  Tile 64x8, 4 waves, wave = 2 rows.
// ---------------------------------------------------------------------------
template <bool RESID>
__global__ __launch_bounds__(256) void conv3x3_mfma(
    const bf16* __restrict__ in, const bf16* __restrict__ wB,
    const float* __restrict__ bias, const bf16* __restrict__ resid,
    bf16* __restrict__ out) {
    __shared__ bf16 tile[10 * 66 * 40];    // [y 10][x 66][ci pitch 40]
    const int x0 = blockIdx.x * 64, y0 = blockIdx.y * 8, b = blockIdx.z;
    const int tid = threadIdx.x;
    const int lane = tid & 63, wv = tid >> 6;
    const int col = lane & 15, gq = lane >> 4;

    bf16x8 Bf[9][2];
    #pragma unroll
    for (int tap = 0; tap < 9; ++tap)
        #pragma unroll
        for (int cb = 0; cb < 2; ++cb)
            Bf[tap][cb] = *reinterpret_cast<const bf16x8*>(
                wB + tap * 1024 + (cb * 16 + col) * 32 + gq * 8);
    const float b0 = bias[col], b1 = bias[16 + col];

    const bf16* inb = in + (size_t)b * NPIX * 32;
    for (int i = tid; i < 2640; i += 256) {        // 10*66*4
        int yy = i / 264, r = i % 264;
        int xx = r >> 2, cg = r & 3;
        int gy = y0 + yy - 1, gx = x0 + xx - 1;
        bf16x8 v = bzero8();
        if ((unsigned)gy < HH && (unsigned)gx < WW)
            v = *reinterpret_cast<const bf16x8*>(inb + ((size_t)gy * WW + gx) * 32 + cg * 8);
        *reinterpret_cast<bf16x8*>(&tile[(yy * 66 + xx) * 40 + cg * 8]) = v;
    }

    f32x4 acc[8][2];
    #pragma unroll
    for (int m = 0; m < 8; ++m) {
        acc[m][0] = {b0, b0, b0, b0};
        acc[m][1] = {b1, b1, b1, b1};
    }
    __syncthreads();

    #pragma unroll
    for (int m = 0; m < 8; ++m) {
        const int row = 2 * wv + (m >> 2), xb = m & 3;
        #pragma unroll
        for (int tap = 0; tap < 9; ++tap) {
            const int dy = tap / 3, dx = tap % 3;
            bf16x8 A = *reinterpret_cast<const bf16x8*>(
                &tile[((row + dy) * 66 + xb * 16 + col + dx) * 40 + gq * 8]);
            acc[m][0] = __builtin_amdgcn_mfma_f32_16x16x32_bf16(A, Bf[tap][0], acc[m][0], 0, 0, 0);
            acc[m][1] = __builtin_amdgcn_mfma_f32_16x16x32_bf16(A, Bf[tap][1], acc[m][1], 0, 0, 0);
        }
    }

    bf16* outb = out + (size_t)b * NPIX * 32;
    const bf16* resb = RESID ? (resid + (size_t)b * NPIX * 32) : nullptr;
    #pragma unroll
    for (int m = 0; m < 8; ++m) {
        const int y = y0 + 2 * wv + (m >> 2);
        const int xbase = x0 + (m & 3) * 16 + gq * 4;
        #pragma unroll
        for (int cb = 0; cb < 2; ++cb) {
            const int co = cb * 16 + col;
            #pragma unroll
            for (int j = 0; j < 4; ++j) {
                size_t a = ((size_t)y * WW + xbase + j) * 32 + co;
                float v = acc[m][cb][j];
                if (RESID) v += (float)resb[a];
                outb[a] = (bf16)fmaxf(v, 0.0f);
            }
        }
    }
}

// ---------------------------------------------------------------------------
// final conv3x3 (128->32), 4 ci-chunks through one LDS buffer, out fp32 NCHW
// Wfin: [chunk 4][tap 9][co 32][ci 32]
// ---------------------------------------------------------------------------
__global__ __launch_bounds__(256) void final_conv_mfma(
    const bf16* __restrict__ pred, const bf16* __restrict__ Wfin,
    const float* __restrict__ bfin, float* __restrict__ out) {
    __shared__ bf16 tile[10 * 66 * 40];
    const int x0 = blockIdx.x * 64, y0 = blockIdx.y * 8, b = blockIdx.z;
    const int tid = threadIdx.x;
    const int lane = tid & 63, wv = tid >> 6;
    const int col = lane & 15, gq = lane >> 4;

    const float b0 = bfin[col], b1 = bfin[16 + col];
    f32x4 acc[8][2];
    #pragma unroll
    for (int m = 0; m < 8; ++m) {
        acc[m][0] = {b0, b0, b0, b0};
        acc[m][1] = {b1, b1, b1, b1};
    }

    for (int chunk = 0; chunk < 4; ++chunk) {
        if (chunk) __syncthreads();
        const bf16* inb = pred + (size_t)b * NPIX * 128 + chunk * 32;
        for (int i = tid; i < 2640; i += 256) {
            int yy = i / 264, r = i % 264;
            int xx = r >> 2, cg = r & 3;
            int gy = y0 + yy - 1, gx = x0 + xx - 1;
            bf16x8 v = bzero8();
            if ((unsigned)gy < HH && (unsigned)gx < WW)
                v = *reinterpret_cast<const bf16x8*>(inb + ((size_t)gy * WW + gx) * 128 + cg * 8);
            *reinterpret_cast<bf16x8*>(&tile[(yy * 66 + xx) * 40 + cg * 8]) = v;
        }
        bf16x8 Bf[9][2];
        #pragma unroll
        for (int tap = 0; tap < 9; ++tap)
            #pragma unroll
            for (int cb = 0; cb < 2; ++cb)
                Bf[tap][cb] = *reinterpret_cast<const bf16x8*>(
                    Wfin + chunk * 9216 + tap * 1024 + (cb * 16 + col) * 32 + gq * 8);
        __syncthreads();

        #pragma unroll
        for (int m = 0; m < 8; ++m) {
            const int row = 2 * wv + (m >> 2), xb = m & 3;
            #pragma unroll
            for (int tap = 0; tap < 9; ++tap) {
                const int dy = tap / 3, dx = tap % 3;
                bf16x8 A = *reinterpret_cast<const bf16x8*>(
                    &tile[((row + dy) * 66 + xb * 16 + col + dx) * 40 + gq * 8]);
                acc[m][0] = __builtin_amdgcn_mfma_f32_16x16x32_bf16(A, Bf[tap][0], acc[m][0], 0, 0, 0);
                acc[m][1] = __builtin_amdgcn_mfma_f32_16x16x32_bf16(A, Bf[tap][1], acc[m][1], 0, 0, 0);
            }
        }
    }

    #pragma unroll
    for (int m = 0; m < 8; ++m) {
        const int y = y0 + 2 * wv + (m >> 2);
        const int xbase = x0 + (m & 3) * 16 + gq * 4;
        #pragma unroll
        for (int cb = 0; cb < 2; ++cb) {
            const int co = cb * 16 + col;
            #pragma unroll
            for (int j = 0; j < 4; ++j)
                out[(size_t)(b * 32 + co) * NPIX + (size_t)y * WW + xbase + j] = acc[m][cb][j];
        }
    }
}

// ---------------------------------------------------------------------------
// fused: m5 = relu(m - tau); core = 1x1 conv via MFMA (permuted cols so each
// lane's nn is fixed); kernel_pred for rates 1..4 accumulated in registers.
// Wcore: [tap 9][nn 32][ci 32].  pred out: [b][y][x][r*32+nn] bf16.
// ---------------------------------------------------------------------------
__global__ __launch_bounds__(256) void core_pred_mfma(
    const bf16* __restrict__ m, const bf16* __restrict__ frames,
    const float* __restrict__ tau, const bf16* __restrict__ Wcore,
    const float* __restrict__ b_outc, bf16* __restrict__ pred) {
    extern __shared__ char smem[];
    bf16* m5t = (bf16*)smem;              // [512 pix][pitch 40]
    bf16* ft  = (bf16*)(smem + 40960);    // [y 16][x 72][pitch 40]
    const int x0 = blockIdx.x * 64, y0 = blockIdx.y * 8, b = blockIdx.z;
    const int tid = threadIdx.x;
    const int lane = tid & 63, wv = tid >> 6;
    const int col = lane & 15, gq = lane >> 4;

    bf16x8 Bc[9][2];
    #pragma unroll
    for (int tap = 0; tap < 9; ++tap)
        #pragma unroll
        for (int half = 0; half < 2; ++half)
            Bc[tap][half] = *reinterpret_cast<const bf16x8*>(
                Wcore + tap * 1024 + (half * 16 + col) * 32 + gq * 8);

    const bf16* mb = m + (size_t)b * NPIX * 32;
    for (int i = tid; i < 2048; i += 256) {      // 512*4
        int p = i >> 2, cg = i & 3;
        int y = y0 + (p >> 6), x = x0 + (p & 63);
        bf16x8 v = *reinterpret_cast<const bf16x8*>(mb + ((size_t)y * WW + x) * 32 + cg * 8);
        #pragma unroll
        for (int j = 0; j < 8; ++j)
            v[j] = (bf16)fmaxf((float)v[j] - tau[cg * 8 + j], 0.0f);
        *reinterpret_cast<bf16x8*>(m5t + p * 40 + cg * 8) = v;
    }
    const bf16* fb = frames + (size_t)b * NPIX * 32;
    for (int i = tid; i < 4608; i += 256) {      // 16*72*4
        int yy = i / 288, r = i % 288;
        int xx = r >> 2, cg = r & 3;
        int gy = y0 + yy - 4, gx = x0 + xx - 4;
        bf16x8 v = bzero8();
        if ((unsigned)gy < HH && (unsigned)gx < WW)
            v = *reinterpret_cast<const bf16x8*>(fb + ((size_t)gy * WW + gx) * 32 + cg * 8);
        *reinterpret_cast<bf16x8*>(ft + (yy * 72 + xx) * 40 + cg * 8) = v;
    }
    __syncthreads();

    bf16* pb = pred + (size_t)b * NPIX * 128;
    #pragma unroll
    for (int mi = 0; mi < 8; ++mi) {
        const int row = 2 * wv + (mi >> 2), xb = mi & 3;
        bf16x8 A = *reinterpret_cast<const bf16x8*>(
            m5t + (row * 64 + xb * 16 + col) * 40 + gq * 8);
        #pragma unroll
        for (int half = 0; half < 2; ++half) {
            const int nn = half * 16 + col;
            float pa[4][4];
            #pragma unroll
            for (int r = 0; r < 4; ++r)
                #pragma unroll
                for (int j = 0; j < 4; ++j) pa[r][j] = 0.0f;
            #pragma unroll
            for (int tap = 0; tap < 9; ++tap) {
                const float bv = b_outc[nn * 9 + tap];
                f32x4 c4 = {bv, bv, bv, bv};
                c4 = __builtin_amdgcn_mfma_f32_16x16x32_bf16(A, Bc[tap][half], c4, 0, 0, 0);
                const int dy = tap / 3 - 1, dx = tap % 3 - 1;
                #pragma unroll
                for (int j = 0; j < 4; ++j) {
                    const int px = xb * 16 + gq * 4 + j;
                    #pragma unroll
                    for (int r = 1; r <= 4; ++r) {
                        float fv = (float)ft[((row + 4 + dy * r) * 72 + px + 4 + dx * r) * 40 + nn];
                        pa[r - 1][j] += c4[j] * fv;
                    }
                }
            }
            const int y = y0 + row;
            #pragma unroll
            for (int j = 0; j < 4; ++j) {
                const int x = x0 + xb * 16 + gq * 4 + j;
                #pragma unroll
                for (int r = 0; r < 4; ++r)
                    pb[((size_t)y * WW + x) * 128 + r * 32 + nn] = (bf16)pa[r][j];
            }
        }
    }
}

// ---------------------------------------------------------------------------
extern "C" void kernel_launch(void* const* d_in, const int* in_sizes, int n_in,
                              void* d_out, int out_size, void* d_ws, size_t ws_size,
                              hipStream_t stream) {
    const float* input    = (const float*)d_in[0];
    const float* wconv    = (const float*)d_in[1];
    const float* bconv    = (const float*)d_in[2];
    const float* bn_gamma = (const float*)d_in[3];
    const float* bn_beta  = (const float*)d_in[4];
    const float* bn_mean  = (const float*)d_in[5];
    const float* bn_var   = (const float*)d_in[6];
    const float* tau      = (const float*)d_in[7];
    const float* w_outc   = (const float*)d_in[8];
    const float* b_outc   = (const float*)d_in[9];
    const float* w_final  = (const float*)d_in[10];
    const float* b_final  = (const float*)d_in[11];
    float* out = (float*)d_out;

    char* ws = (char*)d_ws;
    bf16*  Wres  = (bf16*)(ws);                       // 73728 el -> 147456 B
    float* Bres  = (float*)(ws + 147456);             // 256 el  -> 1024 B
    bf16*  Wcore = (bf16*)(ws + 148480);              // 9216 el -> 18432 B
    bf16*  Wfin  = (bf16*)(ws + 166912);              // 36864 el-> 73728 B
    bf16*  in0b  = (bf16*)(ws + 240640);              // 16777216 B
    bf16*  actA  = (bf16*)(ws + 240640 + 16777216ull);
    bf16*  actB  = (bf16*)(ws + 240640 + 2 * 16777216ull);
    bf16*  actC  = (bf16*)(ws + 240640 + 3 * 16777216ull);
    bf16*  pred  = (bf16*)(ws + 240640 + 4 * 16777216ull);  // 67108864 B

    hipFuncSetAttribute(reinterpret_cast<const void*>(&core_pred_mfma),
                        hipFuncAttributeMaxDynamicSharedMemorySize, 133120);

    prep_in<<<1024, 256, 0, stream>>>(input, in0b);
    fold_w<<<470, 256, 0, stream>>>(wconv, bconv, bn_gamma, bn_beta, bn_mean, bn_var,
                                    w_outc, w_final, Wres, Bres, Wcore, Wfin);

    dim3 grid(4, 32, 4), blk(256);
    conv3x3_mfma<false><<<grid, blk, 0, stream>>>(in0b, Wres + 0 * 9216, Bres + 0,   nullptr, actA);
    conv3x3_mfma<true ><<<grid, blk, 0, stream>>>(actA, Wres + 1 * 9216, Bres + 32,  in0b,    actB);
    conv3x3_mfma<false><<<grid, blk, 0, stream>>>(actB, Wres + 2 * 9216, Bres + 64,  nullptr, actA);
    conv3x3_mfma<true ><<<grid, blk, 0, stream>>>(actA, Wres + 3 * 9216, Bres + 96,  actB,    actC);
    conv3x3_mfma<false><<<grid, blk, 0, stream>>>(actC, Wres + 4 * 9216, Bres + 128, nullptr, actA);
    conv3x3_mfma<true ><<<grid, blk, 0, stream>>>(actA, Wres + 5 * 9216, Bres + 160, actC,    actB);
    conv3x3_mfma<false><<<grid, blk, 0, stream>>>(actB, Wres + 6 * 9216, Bres + 192, nullptr, actA);
    conv3x3_mfma<true ><<<grid, blk, 0, stream>>>(actA, Wres + 7 * 9216, Bres + 224, actB,    actC);

    core_pred_mfma<<<grid, blk, 133120, stream>>>(actC, in0b, tau, Wcore, b_outc, pred);
    final_conv_mfma<<<grid, blk, 0, stream>>>(pred, Wfin, b_final, out);
}